// Round 1
// baseline (544.461 us; speedup 1.0000x reference)
//
#include <hip/hip_runtime.h>

#define PTS   4096
#define NCLOUD  16
#define TPB    256
#define CAP     64

// insert key into unsorted top-16 (s holds the 16 smallest seen, cmax = max of s)
__device__ __forceinline__ void ins16(unsigned int key, unsigned int (&s)[16],
                                      unsigned int &cmax) {
  if (key < cmax) {
    bool done = false;
#pragma unroll
    for (int i = 0; i < 16; ++i) {
      bool c = (!done) && (s[i] == cmax);
      s[i] = c ? key : s[i];
      done = done || c;
    }
    cmax = s[0];
#pragma unroll
    for (int i = 1; i < 16; ++i) cmax = (s[i] > cmax) ? s[i] : cmax;
  }
}

// packed selection key: masked distance bits | candidate index; self -> UINT_MAX
__device__ __forceinline__ unsigned int distkey(const float4 q, const float px,
                                                const float py, const float pz,
                                                const float sqp, const int t,
                                                const int p) {
  float dot = fmaf(pz, q.z, fmaf(py, q.y, px * q.x));
  float d   = fmaf(-2.0f, dot, sqp + q.w);
  d = fmaxf(d, 0.0f);  // guard fp-negative tiny distances (sign bit breaks uint order)
  unsigned int kb = (__float_as_uint(d) & 0xFFFFF000u) | (unsigned int)t;
  return (t == p) ? 0xFFFFFFFFu : kb;
}

__global__ __launch_bounds__(TPB) void knn_cov(const float* __restrict__ x,
                                               float* __restrict__ out) {
  __shared__ float4       spts[PTS];        // 64 KB: x,y,z,|q|^2
  __shared__ unsigned int scol[CAP * TPB];  // 64 KB: per-thread collect columns

  const int tid   = threadIdx.x;
  const int cloud = blockIdx.x >> 4;          // 16 blocks per cloud
  const int p     = ((blockIdx.x & 15) << 8) + tid;  // in-cloud point index

  // stage cloud into LDS with precomputed squared norm
  const float* xc = x + (size_t)cloud * PTS * 3;
  for (int i = tid; i < PTS; i += TPB) {
    float a = xc[i * 3 + 0], b = xc[i * 3 + 1], c = xc[i * 3 + 2];
    spts[i] = make_float4(a, b, c, fmaf(c, c, fmaf(b, b, a * a)));
  }
  __syncthreads();

  const float4 me = spts[p];
  const float px = me.x, py = me.y, pz = me.z, sqp = me.w;

  // ---- pass 1: 32 substream minima (event-free, 2 ops/candidate selection cost)
  unsigned int m[32];
#pragma unroll
  for (int j = 0; j < 32; ++j) m[j] = 0xFFFFFFFFu;
  for (int t0 = 0; t0 < PTS; t0 += 32) {
#pragma unroll
    for (int j = 0; j < 32; ++j) {
      unsigned int kb = distkey(spts[t0 + j], px, py, pz, sqp, t0 + j, p);
      m[j] = (kb < m[j]) ? kb : m[j];
    }
  }

  // ---- threshold = 16th smallest of the 32 minima (provably >= true 16th key)
  unsigned int s[16], cmax;
#pragma unroll
  for (int j = 0; j < 16; ++j) s[j] = m[j];
  cmax = s[0];
#pragma unroll
  for (int j = 1; j < 16; ++j) cmax = (s[j] > cmax) ? s[j] : cmax;
#pragma unroll
  for (int j = 16; j < 32; ++j) ins16(m[j], s, cmax);
  const unsigned int Tkey = cmax;

  // ---- pass 2: collect all keys <= Tkey into LDS (cheap events, conflict-free)
  unsigned int cnt = 0;
  for (int t0 = 0; t0 < PTS; t0 += 8) {
#pragma unroll
    for (int j = 0; j < 8; ++j) {
      const int t = t0 + j;
      unsigned int kb = distkey(spts[t], px, py, pz, sqp, t, p);
      if (kb <= Tkey) {
        if (cnt < (unsigned)CAP) scol[cnt * TPB + tid] = kb;
        cnt++;
      }
    }
  }

  // ---- final selection: top-16 of the collected list (guaranteed cnt >= 16)
  unsigned int wm = cnt;  // wave-uniform loop bound
#pragma unroll
  for (int off = 32; off >= 1; off >>= 1) {
    unsigned int o = __shfl_xor(wm, off, 64);
    wm = (o > wm) ? o : wm;
  }
  const unsigned int nc   = (cnt < (unsigned)CAP) ? cnt : (unsigned)CAP;
  const unsigned int wcap = (wm < (unsigned)CAP) ? wm : (unsigned)CAP;

#pragma unroll
  for (int j = 0; j < 16; ++j) s[j] = scol[j * TPB + tid];
  cmax = s[0];
#pragma unroll
  for (int j = 1; j < 16; ++j) cmax = (s[j] > cmax) ? s[j] : cmax;
  for (unsigned int j = 16; j < wcap; ++j) {
    unsigned int kb = (j < nc) ? scol[j * TPB + tid] : 0xFFFFFFFFu;
    ins16(kb, s, cmax);
  }

  // ---- overflow fallback (P ~ 1e-9/thread): exact rescan with register insert
  if (cnt > (unsigned)CAP) {
#pragma unroll
    for (int j = 0; j < 16; ++j) s[j] = 0xFFFFFFFFu;
    cmax = 0xFFFFFFFFu;
#pragma unroll 2
    for (int t = 0; t < PTS; ++t)
      ins16(distkey(spts[t], px, py, pz, sqp, t, p), s, cmax);
  }

  // ---- gather neighbors + covariance
  float nx[16], ny[16], nz[16];
  float sx = 0.f, sy = 0.f, sz = 0.f;
#pragma unroll
  for (int j = 0; j < 16; ++j) {
    float4 n = spts[s[j] & 0xFFFu];
    nx[j] = n.x; ny[j] = n.y; nz[j] = n.z;
    sx += n.x; sy += n.y; sz += n.z;
  }
  const float mx = sx * 0.0625f, my = sy * 0.0625f, mz = sz * 0.0625f;
  float cxx = 0.f, cxy = 0.f, cxz = 0.f, cyy = 0.f, cyz = 0.f, czz = 0.f;
#pragma unroll
  for (int j = 0; j < 16; ++j) {
    float dx = nx[j] - mx, dy = ny[j] - my, dz = nz[j] - mz;
    cxx = fmaf(dx, dx, cxx); cxy = fmaf(dx, dy, cxy); cxz = fmaf(dx, dz, cxz);
    cyy = fmaf(dy, dy, cyy); cyz = fmaf(dy, dz, cyz); czz = fmaf(dz, dz, czz);
  }
  const float sc = 0.0625f;  // 1/K exact
  const int gid = cloud * PTS + p;
  float4* o = (float4*)(out + (size_t)gid * 12);
  o[0] = make_float4(px, py, pz, cxx * sc);
  o[1] = make_float4(cxy * sc, cxz * sc, cxy * sc, cyy * sc);
  o[2] = make_float4(cyz * sc, cxz * sc, cyz * sc, czz * sc);
}

extern "C" void kernel_launch(void* const* d_in, const int* in_sizes, int n_in,
                              void* d_out, int out_size, void* d_ws, size_t ws_size,
                              hipStream_t stream) {
  const float* x = (const float*)d_in[0];
  float* out = (float*)d_out;
  dim3 grid(NCLOUD * (PTS / TPB));  // 16 clouds x 16 chunks = 256 blocks (1/CU)
  knn_cov<<<grid, TPB, 0, stream>>>(x, out);
}

// Round 2
// 325.891 us; speedup vs baseline: 1.6707x; 1.6707x over previous
//
#include <hip/hip_runtime.h>

#define PTS    4096
#define TPB    256
#define PPB    128          // points per block
#define HALF   2048         // candidates scanned per thread (2-way split)
#define NSUB   64           // substream minima per thread
#define CAP    30           // collect buffer slots per thread
#define NCLOUD 16

typedef __attribute__((ext_vector_type(2))) float f32x2;

// insert key into unsorted top-N (s holds the N smallest seen, cmax = max of s)
template<int N>
__device__ __forceinline__ void insN(unsigned key, unsigned (&s)[N], unsigned &cmax) {
  if (key < cmax) {
    bool done = false;
#pragma unroll
    for (int i = 0; i < N; ++i) {
      bool c = (!done) && (s[i] == cmax);
      s[i] = c ? key : s[i];
      done = done || c;
    }
    cmax = s[0];
#pragma unroll
    for (int i = 1; i < N; ++i) cmax = (s[i] > cmax) ? s[i] : cmax;
  }
}

__global__ __launch_bounds__(TPB, 2) void knn_cov(const float* __restrict__ x,
                                                  float* __restrict__ out) {
  __shared__ float4   pxy[PTS / 2];      // {x0,x1,y0,y1} per candidate pair: 32 KB
  __shared__ f32x2    pzz[PTS / 2];      // {z0,z1} per pair: 16 KB
  __shared__ unsigned scol[CAP * TPB];   // per-thread collect columns: 30 KB
  __shared__ unsigned scnt[TPB];         // 1 KB   (total 79 KB -> 2 blocks/CU)

  const int tid   = threadIdx.x;
  const int cloud = blockIdx.x >> 5;          // 32 blocks per cloud
  const int chunk = blockIdx.x & 31;
  const int pl    = tid & (PPB - 1);
  const int h     = tid >> 7;                 // candidate half handled
  const int p     = chunk * PPB + pl;         // in-cloud point index

  // ---- stage cloud into LDS, pair-packed
  const float* xc = x + (size_t)cloud * PTS * 3;
  for (int i = tid; i < PTS / 2; i += TPB) {
    float x0 = xc[i * 6 + 0], y0 = xc[i * 6 + 1], z0 = xc[i * 6 + 2];
    float x1 = xc[i * 6 + 3], y1 = xc[i * 6 + 4], z1 = xc[i * 6 + 5];
    pxy[i] = make_float4(x0, x1, y0, y1);
    f32x2 zz; zz.x = z0; zz.y = z1;
    pzz[i] = zz;
  }
  __syncthreads();

  // ---- own query point
  {
  }
  const float4 mq = pxy[p >> 1];
  const f32x2  mz = pzz[p >> 1];
  const int odd = p & 1;
  const float px = odd ? mq.y : mq.x;
  const float py = odd ? mq.w : mq.z;
  const float pz = odd ? mz.y : mz.x;
  f32x2 vpx; vpx.x = px; vpx.y = px;
  f32x2 vpy; vpy.x = py; vpy.y = py;
  f32x2 vpz; vpz.x = pz; vpz.y = pz;

  const int c0 = h * HALF;

  // ---- pass 1: 64 substream minima of raw f32 distances (no pack, no self-check)
  float m[NSUB];
#pragma unroll
  for (int j = 0; j < NSUB; ++j) m[j] = 3.4e38f;
  for (int t0 = c0; t0 < c0 + HALF; t0 += NSUB) {
#pragma unroll
    for (int j = 0; j < NSUB; j += 2) {
      const int tp = (t0 + j) >> 1;
      const float4 q = pxy[tp];
      const f32x2 qz = pzz[tp];
      f32x2 xp; xp.x = q.x; xp.y = q.y;
      f32x2 yp; yp.x = q.z; yp.y = q.w;
      const f32x2 dx = xp - vpx, dy = yp - vpy, dz = qz - vpz;
      const f32x2 d = dx * dx + dy * dy + dz * dz;
      m[j]     = fminf(m[j], d.x);
      m[j + 1] = fminf(m[j + 1], d.y);
    }
  }

  // ---- threshold = 17th smallest of the 64 minima (rank 17 absorbs self d=0;
  //      provably >= true 16th-neighbor distance of this half)
  unsigned s17[17], cm;
#pragma unroll
  for (int j = 0; j < 17; ++j) s17[j] = __float_as_uint(m[j]);
  cm = s17[0];
#pragma unroll
  for (int j = 1; j < 17; ++j) cm = (s17[j] > cm) ? s17[j] : cm;
#pragma unroll
  for (int j = 17; j < NSUB; ++j) insN<17>(__float_as_uint(m[j]), s17, cm);
  const float Tval = __uint_as_float(cm);

  // ---- pass 2: collect all candidates with d <= Tval (key pack only on event)
  unsigned cnt = 0;
  for (int t0 = c0; t0 < c0 + HALF; t0 += 16) {
#pragma unroll
    for (int j = 0; j < 16; j += 2) {
      const int tp = (t0 + j) >> 1;
      const float4 q = pxy[tp];
      const f32x2 qz = pzz[tp];
      f32x2 xp; xp.x = q.x; xp.y = q.y;
      f32x2 yp; yp.x = q.z; yp.y = q.w;
      const f32x2 dx = xp - vpx, dy = yp - vpy, dz = qz - vpz;
      const f32x2 d = dx * dx + dy * dy + dz * dz;
      if (d.x <= Tval) {
        unsigned kb = (__float_as_uint(d.x) & 0xFFFFF000u) | (unsigned)(t0 + j);
        if (cnt < (unsigned)CAP) scol[cnt * TPB + tid] = kb;
        cnt++;
      }
      if (d.y <= Tval) {
        unsigned kb = (__float_as_uint(d.y) & 0xFFFFF000u) | (unsigned)(t0 + j + 1);
        if (cnt < (unsigned)CAP) scol[cnt * TPB + tid] = kb;
        cnt++;
      }
    }
  }

  // ---- overflow fallback (~5.6 sigma, essentially never): exact rescan
  if (cnt > (unsigned)CAP) {
    unsigned s16[16], cm16 = 0xFFFFFFFFu;
#pragma unroll
    for (int j = 0; j < 16; ++j) s16[j] = 0xFFFFFFFFu;
    for (int t = c0; t < c0 + HALF; t += 2) {
      const int tp = t >> 1;
      const float4 q = pxy[tp];
      const f32x2 qz = pzz[tp];
      f32x2 xp; xp.x = q.x; xp.y = q.y;
      f32x2 yp; yp.x = q.z; yp.y = q.w;
      const f32x2 dx = xp - vpx, dy = yp - vpy, dz = qz - vpz;
      const f32x2 d = dx * dx + dy * dy + dz * dz;
      unsigned k0 = (t == p) ? 0xFFFFFFFFu
                             : ((__float_as_uint(d.x) & 0xFFFFF000u) | (unsigned)t);
      unsigned k1 = (t + 1 == p) ? 0xFFFFFFFFu
                                 : ((__float_as_uint(d.y) & 0xFFFFF000u) | (unsigned)(t + 1));
      insN<16>(k0, s16, cm16);
      insN<16>(k1, s16, cm16);
    }
#pragma unroll
    for (int j = 0; j < 16; ++j) scol[j * TPB + tid] = s16[j];
    cnt = 16;
  }
  scnt[tid] = (cnt < (unsigned)CAP) ? cnt : (unsigned)CAP;
  __syncthreads();

  // ---- merge the two halves' candidate sets (threads 0..127), cov, store
  if (tid < PPB) {
    const unsigned n0 = scnt[tid], n1 = scnt[tid + PPB];
    unsigned w0 = n0, w1 = n1;
#pragma unroll
    for (int off = 32; off >= 1; off >>= 1) {
      unsigned o0 = (unsigned)__shfl_xor((int)w0, off, 64);
      unsigned o1 = (unsigned)__shfl_xor((int)w1, off, 64);
      w0 = (o0 > w0) ? o0 : w0;
      w1 = (o1 > w1) ? o1 : w1;
    }
    unsigned s16[16], cm16 = 0xFFFFFFFFu;
#pragma unroll
    for (int j = 0; j < 16; ++j) s16[j] = 0xFFFFFFFFu;
    const unsigned selfk = (unsigned)p;  // self key: d==+0 exactly -> bits 0 | p
    for (unsigned j = 0; j < w0; ++j) {
      unsigned kb = (j < n0) ? scol[j * TPB + tid] : 0xFFFFFFFFu;
      kb = (kb == selfk) ? 0xFFFFFFFFu : kb;
      insN<16>(kb, s16, cm16);
    }
    for (unsigned j = 0; j < w1; ++j) {
      unsigned kb = (j < n1) ? scol[j * TPB + tid + PPB] : 0xFFFFFFFFu;
      kb = (kb == selfk) ? 0xFFFFFFFFu : kb;
      insN<16>(kb, s16, cm16);
    }

    // raw moments -> covariance (f32 error ~1e-5 << 9e-2 threshold)
    float Sx = 0, Sy = 0, Sz = 0;
    float Sxx = 0, Sxy = 0, Sxz = 0, Syy = 0, Syz = 0, Szz = 0;
#pragma unroll
    for (int j = 0; j < 16; ++j) {
      const unsigned idx = s16[j] & 0xFFFu;
      const float4 q = pxy[idx >> 1];
      const f32x2 qz = pzz[idx >> 1];
      const int o = idx & 1;
      const float nx = o ? q.y : q.x;
      const float ny = o ? q.w : q.z;
      const float nz = o ? qz.y : qz.x;
      Sx += nx; Sy += ny; Sz += nz;
      Sxx = fmaf(nx, nx, Sxx); Sxy = fmaf(nx, ny, Sxy); Sxz = fmaf(nx, nz, Sxz);
      Syy = fmaf(ny, ny, Syy); Syz = fmaf(ny, nz, Syz); Szz = fmaf(nz, nz, Szz);
    }
    const float sc = 0.0625f;
    const float mx = Sx * sc, my = Sy * sc, mzv = Sz * sc;
    const float cxx = fmaf(-mx, mx, Sxx * sc);
    const float cxy = fmaf(-mx, my, Sxy * sc);
    const float cxz = fmaf(-mx, mzv, Sxz * sc);
    const float cyy = fmaf(-my, my, Syy * sc);
    const float cyz = fmaf(-my, mzv, Syz * sc);
    const float czz = fmaf(-mzv, mzv, Szz * sc);

    const int gid = cloud * PTS + p;
    float4* o4 = (float4*)(out + (size_t)gid * 12);
    o4[0] = make_float4(px, py, pz, cxx);
    o4[1] = make_float4(cxy, cxz, cxy, cyy);
    o4[2] = make_float4(cyz, cxz, cyz, czz);
  }
}

extern "C" void kernel_launch(void* const* d_in, const int* in_sizes, int n_in,
                              void* d_out, int out_size, void* d_ws, size_t ws_size,
                              hipStream_t stream) {
  const float* x = (const float*)d_in[0];
  float* out = (float*)d_out;
  dim3 grid(NCLOUD * (PTS / PPB));  // 16 clouds x 32 chunks = 512 blocks
  knn_cov<<<grid, TPB, 0, stream>>>(x, out);
}

// Round 3
// 201.817 us; speedup vs baseline: 2.6978x; 1.6148x over previous
//
#include <hip/hip_runtime.h>

#define PTS    4096
#define TPB    256
#define PPB    64      // points per block (one per lane of the merge wave)
#define QTR    1024    // candidates scanned per thread (4-way split)
#define NSUB   64      // substream minima per thread (pass 1)
#define CAP    36      // collect slots per thread
#define NCLOUD 16
#define UMAX   0xFFFFFFFFu

// insert key into unsorted top-N (s holds the N smallest seen, cmax = max of s)
template<int N>
__device__ __forceinline__ void insN(unsigned key, unsigned (&s)[N], unsigned &cmax) {
  if (key < cmax) {
    bool done = false;
#pragma unroll
    for (int i = 0; i < N; ++i) {
      bool c = (!done) && (s[i] == cmax);
      s[i] = c ? key : s[i];
      done = done || c;
    }
    cmax = s[0];
#pragma unroll
    for (int i = 1; i < N; ++i) cmax = (s[i] > cmax) ? s[i] : cmax;
  }
}

__global__ __launch_bounds__(TPB, 4) void knn_cov(const float* __restrict__ x,
                                                  float* __restrict__ out) {
  __shared__ unsigned scol[CAP * TPB];  // 36 KB: per-thread collect columns
  __shared__ unsigned scnt[TPB];        // 1 KB  (total ~37 KB -> 4 blocks/CU)

  const int tid  = threadIdx.x;
  const int lane = tid & 63;
  // wave id: uniform by construction; readfirstlane makes the compiler see it
  // as uniform so candidate loads can go to the scalar (SMEM) path.
  const int h     = __builtin_amdgcn_readfirstlane(tid >> 6);
  const int cloud = blockIdx.x >> 6;          // 64 chunks per cloud
  const int chunk = blockIdx.x & 63;
  const int p     = chunk * PPB + lane;       // in-cloud point for this lane

  const float* __restrict__ xc = x + (size_t)cloud * PTS * 3;

  const float px = xc[p * 3 + 0];
  const float py = xc[p * 3 + 1];
  const float pz = xc[p * 3 + 2];

  const int c0 = h * QTR;                     // this wave's candidate quarter
  const float* __restrict__ cc = xc + (size_t)c0 * 3;

  // ---- pass 1: 64 substream minima, diff-form distance (7 VALU/cand, no DS)
  float m[NSUB];
#pragma unroll
  for (int j = 0; j < NSUB; ++j) m[j] = 3.4e38f;
  for (int t0 = 0; t0 < QTR; t0 += NSUB) {
#pragma unroll
    for (int g = 0; g < NSUB / 8; ++g) {
#pragma unroll
      for (int j = 0; j < 8; ++j) {
        const int ci = t0 + g * 8 + j;
        const float qx = cc[ci * 3 + 0];
        const float qy = cc[ci * 3 + 1];
        const float qz = cc[ci * 3 + 2];
        const float dx = qx - px, dy = qy - py, dz = qz - pz;
        const float d  = fmaf(dz, dz, fmaf(dy, dy, dx * dx));
        const int mi   = g * 8 + j;           // static index
        m[mi] = fminf(m[mi], d);
      }
    }
  }

  // ---- threshold = 17th smallest of 64 minima (rank 17 absorbs self d=0;
  //      >= true 16th-smallest real distance of this quarter)
  unsigned s17[17], cm;
#pragma unroll
  for (int j = 0; j < 17; ++j) s17[j] = __float_as_uint(m[j]);
  cm = s17[0];
#pragma unroll
  for (int j = 1; j < 17; ++j) cm = (s17[j] > cm) ? s17[j] : cm;
#pragma unroll
  for (int j = 17; j < NSUB; ++j) insN<17>(__float_as_uint(m[j]), s17, cm);
  const float Tval = __uint_as_float(cm);

  // ---- pass 2: collect all d <= T into LDS columns (clamped slot, no branch
  //      inside the event block beyond the event itself)
  unsigned cnt = 0;
  for (int t0 = 0; t0 < QTR; t0 += 8) {
#pragma unroll
    for (int j = 0; j < 8; ++j) {
      const int ci = t0 + j;
      const float qx = cc[ci * 3 + 0];
      const float qy = cc[ci * 3 + 1];
      const float qz = cc[ci * 3 + 2];
      const float dx = qx - px, dy = qy - py, dz = qz - pz;
      const float d  = fmaf(dz, dz, fmaf(dy, dy, dx * dx));
      if (d <= Tval) {
        const unsigned slot = (cnt < (unsigned)CAP) ? cnt : (unsigned)(CAP - 1);
        scol[slot * TPB + tid] =
            (__float_as_uint(d) & 0xFFFFF000u) | (unsigned)(c0 + ci);
        cnt++;
      }
    }
  }

  // ---- overflow fallback (rare): exact top-17 rescan of this quarter
  if (cnt > (unsigned)CAP) {
    unsigned sf[17], cmf = UMAX;
#pragma unroll
    for (int j = 0; j < 17; ++j) sf[j] = UMAX;
#pragma unroll 4
    for (int ci = 0; ci < QTR; ++ci) {
      const float qx = cc[ci * 3 + 0];
      const float qy = cc[ci * 3 + 1];
      const float qz = cc[ci * 3 + 2];
      const float dx = qx - px, dy = qy - py, dz = qz - pz;
      const float d  = fmaf(dz, dz, fmaf(dy, dy, dx * dx));
      const unsigned kb = (__float_as_uint(d) & 0xFFFFF000u) | (unsigned)(c0 + ci);
      insN<17>(kb, sf, cmf);
    }
#pragma unroll
    for (int j = 0; j < 17; ++j) scol[j * TPB + tid] = sf[j];
    cnt = 17;
  }
  scnt[tid] = cnt;
  __syncthreads();

  // ---- merge the 4 quarters' candidate sets (wave 0), cov, store
  if (tid < PPB) {
    unsigned s16[16], cm16 = UMAX;
#pragma unroll
    for (int j = 0; j < 16; ++j) s16[j] = UMAX;
    const unsigned selfk = (unsigned)p;  // self: d==+0 exactly -> key = index
#pragma unroll
    for (int k = 0; k < 4; ++k) {
      const int col = k * PPB + tid;
      const unsigned n = scnt[col];
      unsigned w = n;
#pragma unroll
      for (int off = 32; off >= 1; off >>= 1) {
        unsigned o = (unsigned)__shfl_xor((int)w, off, 64);
        w = (o > w) ? o : w;
      }
      for (unsigned j = 0; j < w; ++j) {
        unsigned kb = (j < n) ? scol[j * TPB + col] : UMAX;
        kb = (kb == selfk) ? UMAX : kb;
        insN<16>(kb, s16, cm16);
      }
    }

    // gather neighbor coords (L1/L2-resident), raw moments -> covariance
    float Sx = 0, Sy = 0, Sz = 0;
    float Sxx = 0, Sxy = 0, Sxz = 0, Syy = 0, Syz = 0, Szz = 0;
#pragma unroll
    for (int j = 0; j < 16; ++j) {
      const int idx = (int)(s16[j] & 0xFFFu);
      const float nx = xc[idx * 3 + 0];
      const float ny = xc[idx * 3 + 1];
      const float nz = xc[idx * 3 + 2];
      Sx += nx; Sy += ny; Sz += nz;
      Sxx = fmaf(nx, nx, Sxx); Sxy = fmaf(nx, ny, Sxy); Sxz = fmaf(nx, nz, Sxz);
      Syy = fmaf(ny, ny, Syy); Syz = fmaf(ny, nz, Syz); Szz = fmaf(nz, nz, Szz);
    }
    const float sc = 0.0625f;
    const float mx = Sx * sc, my = Sy * sc, mz = Sz * sc;
    const float cxx = fmaf(-mx, mx, Sxx * sc);
    const float cxy = fmaf(-mx, my, Sxy * sc);
    const float cxz = fmaf(-mx, mz, Sxz * sc);
    const float cyy = fmaf(-my, my, Syy * sc);
    const float cyz = fmaf(-my, mz, Syz * sc);
    const float czz = fmaf(-mz, mz, Szz * sc);

    const int gid = cloud * PTS + p;
    float4* o4 = (float4*)(out + (size_t)gid * 12);
    o4[0] = make_float4(px, py, pz, cxx);
    o4[1] = make_float4(cxy, cxz, cxy, cyy);
    o4[2] = make_float4(cyz, cxz, cyz, czz);
  }
}

extern "C" void kernel_launch(void* const* d_in, const int* in_sizes, int n_in,
                              void* d_out, int out_size, void* d_ws, size_t ws_size,
                              hipStream_t stream) {
  const float* x = (const float*)d_in[0];
  float* out = (float*)d_out;
  dim3 grid(NCLOUD * (PTS / PPB));  // 16 clouds x 64 chunks = 1024 blocks = 4/CU
  knn_cov<<<grid, TPB, 0, stream>>>(x, out);
}